// Round 1
// baseline (152.177 us; speedup 1.0000x reference)
//
#include <hip/hip_runtime.h>
#include <hip/hip_bf16.h>
#include <cmath>

#define B 4
#define NQ 128
#define NK 1024
#define HD 256
#define DV 256

// ---------------------------------------------------------------------------
// proj_tanh: out_t[m,h] = tanh(X[m,:]·W[h,:]),  out_wt[m,h] = wv[h]*tanh(...)
// X: (M, HD) row-major, W: (HD, HD) row-major (used as x @ W^T).
// grid: (M/64, HD/64), block 256. Plain fp32 tiled GEMM (no fp32 MFMA on CDNA4).
// ---------------------------------------------------------------------------
__global__ __launch_bounds__(256) void proj_tanh(const float* __restrict__ X,
                                                 const float* __restrict__ W,
                                                 const float* __restrict__ wv,
                                                 float* __restrict__ wt_out,
                                                 float* __restrict__ t_out)
{
    __shared__ float sX[64][68];   // [d][m], pad 68 keeps rows 16B-aligned
    __shared__ float sW[64][68];   // [d][h]
    const int tid = threadIdx.x;
    const int bm = blockIdx.x * 64;
    const int bh = blockIdx.y * 64;
    const int ty = tid >> 4, tx = tid & 15;
    const int lr = tid >> 2;           // load row 0..63
    const int lc = (tid & 3) << 4;     // load col group 0,16,32,48

    float acc[4][4] = {};

    for (int ks = 0; ks < HD; ks += 64) {
        #pragma unroll
        for (int j = 0; j < 4; ++j) {
            const int d = lc + j * 4;
            float4 xv = *(const float4*)&X[(size_t)(bm + lr) * HD + ks + d];
            float4 wm = *(const float4*)&W[(size_t)(bh + lr) * HD + ks + d];
            sX[d + 0][lr] = xv.x; sX[d + 1][lr] = xv.y;
            sX[d + 2][lr] = xv.z; sX[d + 3][lr] = xv.w;
            sW[d + 0][lr] = wm.x; sW[d + 1][lr] = wm.y;
            sW[d + 2][lr] = wm.z; sW[d + 3][lr] = wm.w;
        }
        __syncthreads();
        #pragma unroll 8
        for (int kk = 0; kk < 64; ++kk) {
            float4 a4 = *(const float4*)&sX[kk][ty * 4];
            float4 b4 = *(const float4*)&sW[kk][tx * 4];
            float av[4] = {a4.x, a4.y, a4.z, a4.w};
            float bv[4] = {b4.x, b4.y, b4.z, b4.w};
            #pragma unroll
            for (int i = 0; i < 4; ++i)
                #pragma unroll
                for (int j = 0; j < 4; ++j)
                    acc[i][j] = fmaf(av[i], bv[j], acc[i][j]);
        }
        __syncthreads();
    }

    const int m0 = bm + ty * 4;
    const int h0 = bh + tx * 4;
    float4 wv4 = *(const float4*)&wv[h0];
    float wvv[4] = {wv4.x, wv4.y, wv4.z, wv4.w};
    #pragma unroll
    for (int i = 0; i < 4; ++i) {
        float t[4];
        #pragma unroll
        for (int j = 0; j < 4; ++j) t[j] = tanhf(acc[i][j]);
        float4 t4  = {t[0], t[1], t[2], t[3]};
        float4 wt4 = {wvv[0] * t[0], wvv[1] * t[1], wvv[2] * t[2], wvv[3] * t[3]};
        *(float4*)&t_out[(size_t)(m0 + i) * HD + h0]  = t4;
        *(float4*)&wt_out[(size_t)(m0 + i) * HD + h0] = wt4;
    }
}

// ---------------------------------------------------------------------------
// scores: scores[b,q,k] = sum_h (wtq+wtk) * rcp(1 + tq*tk)
// (tanh addition formula: tanh(q+k) = (tq+tk)/(1+tq*tk), wv folded into wtq/wtk)
// grid: (NK/32, NQ/32, B), block 256 (16x16 threads, 2x2 micro-tile).
// ---------------------------------------------------------------------------
__global__ __launch_bounds__(256) void scores_kernel(const float* __restrict__ wtq,
                                                     const float* __restrict__ tq,
                                                     const float* __restrict__ wtk,
                                                     const float* __restrict__ tk,
                                                     float* __restrict__ scores)
{
    __shared__ float s_qw[32][68];
    __shared__ float s_qt[32][68];
    __shared__ float s_kw[32][68];   // row-permuted: k row r stored at (r>>1)|((r&1)<<4)
    __shared__ float s_kt[32][68];
    const int tid = threadIdx.x;
    const int kb = blockIdx.x * 32;
    const int qb = blockIdx.y * 32;
    const int b  = blockIdx.z;
    const int ty = tid >> 4, tx = tid & 15;

    float acc00 = 0.f, acc01 = 0.f, acc10 = 0.f, acc11 = 0.f;
    const size_t qbase = ((size_t)b * NQ + qb) * HD;
    const size_t kbase = ((size_t)b * NK + kb) * HD;

    for (int hc = 0; hc < HD; hc += 64) {
        #pragma unroll
        for (int f0 = 0; f0 < 2; ++f0) {
            const int f   = tid + f0 * 256;
            const int row = f >> 4;
            const int col = (f & 15) << 2;
            const int prow = (row >> 1) | ((row & 1) << 4);
            *(float4*)&s_qw[row][col]  = *(const float4*)&wtq[qbase + (size_t)row * HD + hc + col];
            *(float4*)&s_qt[row][col]  = *(const float4*)&tq [qbase + (size_t)row * HD + hc + col];
            *(float4*)&s_kw[prow][col] = *(const float4*)&wtk[kbase + (size_t)row * HD + hc + col];
            *(float4*)&s_kt[prow][col] = *(const float4*)&tk [kbase + (size_t)row * HD + hc + col];
        }
        __syncthreads();

        const int q0 = ty * 2, q1 = q0 + 1;
        const int k0 = tx, k1 = tx + 16;   // permuted rows = actual k rows 2tx, 2tx+1

        #pragma unroll
        for (int i = 0; i < 16; ++i) {
            const int h4 = i << 2;
            float4 v;
            v = *(const float4*)&s_qw[q0][h4]; float qw0[4] = {v.x, v.y, v.z, v.w};
            v = *(const float4*)&s_qt[q0][h4]; float qt0[4] = {v.x, v.y, v.z, v.w};
            v = *(const float4*)&s_qw[q1][h4]; float qw1[4] = {v.x, v.y, v.z, v.w};
            v = *(const float4*)&s_qt[q1][h4]; float qt1[4] = {v.x, v.y, v.z, v.w};
            v = *(const float4*)&s_kw[k0][h4]; float kw0[4] = {v.x, v.y, v.z, v.w};
            v = *(const float4*)&s_kt[k0][h4]; float kt0[4] = {v.x, v.y, v.z, v.w};
            v = *(const float4*)&s_kw[k1][h4]; float kw1[4] = {v.x, v.y, v.z, v.w};
            v = *(const float4*)&s_kt[k1][h4]; float kt1[4] = {v.x, v.y, v.z, v.w};
            #pragma unroll
            for (int j = 0; j < 4; ++j) {
                float n, d;
                n = qw0[j] + kw0[j]; d = fmaf(qt0[j], kt0[j], 1.0f);
                acc00 = fmaf(n, __builtin_amdgcn_rcpf(d), acc00);
                n = qw0[j] + kw1[j]; d = fmaf(qt0[j], kt1[j], 1.0f);
                acc01 = fmaf(n, __builtin_amdgcn_rcpf(d), acc01);
                n = qw1[j] + kw0[j]; d = fmaf(qt1[j], kt0[j], 1.0f);
                acc10 = fmaf(n, __builtin_amdgcn_rcpf(d), acc10);
                n = qw1[j] + kw1[j]; d = fmaf(qt1[j], kt1[j], 1.0f);
                acc11 = fmaf(n, __builtin_amdgcn_rcpf(d), acc11);
            }
        }
        __syncthreads();
    }

    const int qg = qb + ty * 2;
    const int kg = kb + tx * 2;
    const size_t sbase = ((size_t)b * NQ + qg) * NK + kg;
    *(float2*)&scores[sbase]      = make_float2(acc00, acc01);
    *(float2*)&scores[sbase + NK] = make_float2(acc10, acc11);
}

// ---------------------------------------------------------------------------
// softmax over k with mask k < valid_lens[b]; in-place on scores. 1 block/row.
// ---------------------------------------------------------------------------
__global__ __launch_bounds__(256) void softmax_kernel(float* __restrict__ scores,
                                                      const int* __restrict__ valid_lens)
{
    const int row = blockIdx.x;          // 0 .. B*NQ-1
    const int b = row >> 7;              // NQ = 128
    const int valid = valid_lens[b];
    float* s = scores + (size_t)row * NK;
    const int tid = threadIdx.x;

    float4 v = *(const float4*)&s[tid * 4];
    float x[4] = {v.x, v.y, v.z, v.w};
    #pragma unroll
    for (int j = 0; j < 4; ++j) {
        const int k = tid * 4 + j;
        if (k >= valid) x[j] = -1e6f;
    }
    float m = fmaxf(fmaxf(x[0], x[1]), fmaxf(x[2], x[3]));
    #pragma unroll
    for (int off = 32; off >= 1; off >>= 1)
        m = fmaxf(m, __shfl_xor(m, off));

    __shared__ float redm[4], reds[4];
    const int wid = tid >> 6, lane = tid & 63;
    if (lane == 0) redm[wid] = m;
    __syncthreads();
    m = fmaxf(fmaxf(redm[0], redm[1]), fmaxf(redm[2], redm[3]));

    float p[4], psum = 0.f;
    #pragma unroll
    for (int j = 0; j < 4; ++j) { p[j] = __expf(x[j] - m); psum += p[j]; }
    #pragma unroll
    for (int off = 32; off >= 1; off >>= 1)
        psum += __shfl_xor(psum, off);
    if (lane == 0) reds[wid] = psum;
    __syncthreads();
    const float total = reds[0] + reds[1] + reds[2] + reds[3];
    const float inv = 1.0f / total;

    float4 o = {p[0] * inv, p[1] * inv, p[2] * inv, p[3] * inv};
    *(float4*)&s[tid * 4] = o;
}

// ---------------------------------------------------------------------------
// pv_partial: partial[ks][b,q,v] = sum_{k in slice ks} attn[b,q,k]*values[b,k,v]
// grid: (8, NQ/16, B), block 256 (thread = v).
// ---------------------------------------------------------------------------
__global__ __launch_bounds__(256) void pv_partial(const float* __restrict__ attn,
                                                  const float* __restrict__ values,
                                                  float* __restrict__ partial)
{
    __shared__ float s_a[16][128];
    const int tid = threadIdx.x;
    const int ks = blockIdx.x, qg = blockIdx.y, b = blockIdx.z;
    const int q0 = qg * 16;
    const int k0 = ks * 128;

    #pragma unroll
    for (int f0 = 0; f0 < 2; ++f0) {
        const int f = tid + f0 * 256;
        const int row = f >> 5;
        const int col = (f & 31) << 2;
        *(float4*)&s_a[row][col] =
            *(const float4*)&attn[((size_t)b * NQ + q0 + row) * NK + k0 + col];
    }
    __syncthreads();

    float acc[16] = {};
    #pragma unroll 8
    for (int k = 0; k < 128; ++k) {
        const float va = values[((size_t)b * NK + k0 + k) * DV + tid];
        #pragma unroll
        for (int q = 0; q < 16; ++q)
            acc[q] = fmaf(s_a[q][k], va, acc[q]);
    }

    const size_t pbase = (size_t)ks * (B * NQ * DV) + ((size_t)b * NQ + q0) * DV + tid;
    #pragma unroll
    for (int q = 0; q < 16; ++q)
        partial[pbase + (size_t)q * DV] = acc[q];
}

__global__ __launch_bounds__(256) void reduce_pv(const float* __restrict__ partial,
                                                 float* __restrict__ out)
{
    const int i = blockIdx.x * 256 + threadIdx.x;   // 0 .. B*NQ*DV-1
    float s = 0.f;
    #pragma unroll
    for (int p = 0; p < 8; ++p) s += partial[(size_t)p * (B * NQ * DV) + i];
    out[i] = s;
}

// ---------------------------------------------------------------------------
extern "C" void kernel_launch(void* const* d_in, const int* in_sizes, int n_in,
                              void* d_out, int out_size, void* d_ws, size_t ws_size,
                              hipStream_t stream) {
    const float* queries   = (const float*)d_in[0];
    const float* keys      = (const float*)d_in[1];
    const float* values    = (const float*)d_in[2];
    const int*   valid_lens= (const int*)  d_in[3];
    const float* Wq        = (const float*)d_in[4];
    const float* Wk        = (const float*)d_in[5];
    const float* wv        = (const float*)d_in[6];
    float* out = (float*)d_out;

    float* ws      = (float*)d_ws;
    float* wtq     = ws;                       // B*NQ*HD   = 131072
    float* tq      = wtq + (size_t)B * NQ * HD;
    float* wtk     = tq  + (size_t)B * NQ * HD; // B*NK*HD  = 1048576
    float* tk      = wtk + (size_t)B * NK * HD;
    float* scores  = tk  + (size_t)B * NK * HD; // B*NQ*NK  = 524288
    float* partial = scores + (size_t)B * NQ * NK; // 8*B*NQ*DV = 1048576

    proj_tanh<<<dim3((B * NQ) / 64, HD / 64), 256, 0, stream>>>(queries, Wq, wv, wtq, tq);
    proj_tanh<<<dim3((B * NK) / 64, HD / 64), 256, 0, stream>>>(keys, Wk, wv, wtk, tk);
    scores_kernel<<<dim3(NK / 32, NQ / 32, B), 256, 0, stream>>>(wtq, tq, wtk, tk, scores);
    softmax_kernel<<<dim3(B * NQ), 256, 0, stream>>>(scores, valid_lens);
    pv_partial<<<dim3(8, NQ / 16, B), 256, 0, stream>>>(scores, values, partial);
    reduce_pv<<<dim3((B * NQ * DV) / 256), 256, 0, stream>>>(partial, out);
}

// Round 5
// 129.149 us; speedup vs baseline: 1.1783x; 1.1783x over previous
//
#include <hip/hip_runtime.h>
#include <hip/hip_bf16.h>
#include <cmath>

#define B 4
#define NQ 128
#define NK 1024
#define HD 256
#define DV 256

// ---------------------------------------------------------------------------
// proj_exp: E[m,h] = exp(2 * X[m,:]·W[h,:])
// z=0: queries (512 rows), z=1: keys (4096 rows). Same validated GEMM core as
// round 0; epilogue writes a single exp array (tanh folded into the scores
// formulation: wv·tanh(q+k) = wv - 2wv/(1+e^{2q}e^{2k}), Σwv dropped by
// softmax shift-invariance).
// ---------------------------------------------------------------------------
__global__ __launch_bounds__(256) void proj_exp(
    const float* __restrict__ Xq, const float* __restrict__ Xk,
    const float* __restrict__ Wq, const float* __restrict__ Wk,
    float* __restrict__ Eq, float* __restrict__ Ek)
{
    const int z = blockIdx.z;
    if (z == 0 && blockIdx.x >= (B * NQ) / 64) return;   // queries: 8 m-tiles
    const float* __restrict__ X = z ? Xk : Xq;
    const float* __restrict__ W = z ? Wk : Wq;
    float* __restrict__ E = z ? Ek : Eq;

    __shared__ float sX[64][68];   // [k][m], pad 68
    __shared__ float sW[64][68];   // [k][h]
    const int tid = threadIdx.x;
    const int bm = blockIdx.x * 64;
    const int bh = blockIdx.y * 64;
    const int ty = tid >> 4, tx = tid & 15;
    const int lr = tid >> 2;           // load row 0..63
    const int lc = (tid & 3) << 4;     // load col group 0,16,32,48

    float acc[4][4] = {};

    for (int ks = 0; ks < HD; ks += 64) {
        #pragma unroll
        for (int j = 0; j < 4; ++j) {
            const int d = lc + j * 4;
            float4 xv = *(const float4*)&X[(size_t)(bm + lr) * HD + ks + d];
            float4 wm = *(const float4*)&W[(size_t)(bh + lr) * HD + ks + d];
            sX[d + 0][lr] = xv.x; sX[d + 1][lr] = xv.y;
            sX[d + 2][lr] = xv.z; sX[d + 3][lr] = xv.w;
            sW[d + 0][lr] = wm.x; sW[d + 1][lr] = wm.y;
            sW[d + 2][lr] = wm.z; sW[d + 3][lr] = wm.w;
        }
        __syncthreads();
        #pragma unroll 8
        for (int kk = 0; kk < 64; ++kk) {
            float4 a4 = *(const float4*)&sX[kk][ty * 4];
            float4 b4 = *(const float4*)&sW[kk][tx * 4];
            float av[4] = {a4.x, a4.y, a4.z, a4.w};
            float bv[4] = {b4.x, b4.y, b4.z, b4.w};
            #pragma unroll
            for (int i = 0; i < 4; ++i)
                #pragma unroll
                for (int j = 0; j < 4; ++j)
                    acc[i][j] = fmaf(av[i], bv[j], acc[i][j]);
        }
        __syncthreads();
    }

    const int m0 = bm + ty * 4;
    const int h0 = bh + tx * 4;
    #pragma unroll
    for (int i = 0; i < 4; ++i) {
        float4 e4 = {__expf(2.0f * acc[i][0]), __expf(2.0f * acc[i][1]),
                     __expf(2.0f * acc[i][2]), __expf(2.0f * acc[i][3])};
        *(float4*)&E[(size_t)(m0 + i) * HD + h0] = e4;
    }
}

// ---------------------------------------------------------------------------
// scores' = sum_h w2[h] * rcp(1 + eq[q,h]*ek[k,h]),  w2 = -2*wv.
// Quad-combine: 4 h-terms over common denominator -> 1 rcp per 4 elems.
// Tile 32q x 32k, 256 thr, 2x2 micro (rows ty/ty+16, tx/tx+16: 2-way-free
// banks on pad-68). grid (NK/32, NQ/32, B) = 512 blocks = 2/CU.
// ---------------------------------------------------------------------------
__device__ __forceinline__ void quad_acc(float& acc, float4 q, float4 k, float4 w)
{
    float d0 = fmaf(q.x, k.x, 1.0f);
    float d1 = fmaf(q.y, k.y, 1.0f);
    float d2 = fmaf(q.z, k.z, 1.0f);
    float d3 = fmaf(q.w, k.w, 1.0f);
    float n01 = fmaf(w.x, d1, w.y * d0);
    float d01 = d0 * d1;
    float n23 = fmaf(w.z, d3, w.w * d2);
    float d23 = d2 * d3;
    float n  = fmaf(n01, d23, n23 * d01);
    float dd = d01 * d23;
    acc = fmaf(n, __builtin_amdgcn_rcpf(dd), acc);
}

__global__ __launch_bounds__(256) void scores_kernel(
    const float* __restrict__ Eq, const float* __restrict__ Ek,
    const float* __restrict__ wv, float* __restrict__ scores)
{
    __shared__ float s_q[32][68];
    __shared__ float s_k[32][68];
    __shared__ float s_w[64];
    const int tid = threadIdx.x;
    const int kb = blockIdx.x * 32;
    const int qb = blockIdx.y * 32;
    const int b  = blockIdx.z;
    const int ty = tid >> 4, tx = tid & 15;

    float a00 = 0.f, a01 = 0.f, a10 = 0.f, a11 = 0.f;
    const size_t qbase = ((size_t)b * NQ + qb) * HD;
    const size_t kbase = ((size_t)b * NK + kb) * HD;

    const int srow = tid >> 3;         // 0..31
    const int scol = (tid & 7) << 3;   // 0,8,..,56

    for (int hc = 0; hc < HD; hc += 64) {
        {
            const float* qp = &Eq[qbase + (size_t)srow * HD + hc + scol];
            const float* kp = &Ek[kbase + (size_t)srow * HD + hc + scol];
            float4 q0 = *(const float4*)qp;
            float4 q1 = *(const float4*)(qp + 4);
            float4 k0 = *(const float4*)kp;
            float4 k1 = *(const float4*)(kp + 4);
            *(float4*)&s_q[srow][scol]     = q0;
            *(float4*)&s_q[srow][scol + 4] = q1;
            *(float4*)&s_k[srow][scol]     = k0;
            *(float4*)&s_k[srow][scol + 4] = k1;
            if (tid < 16) {
                float4 w = *(const float4*)&wv[hc + tid * 4];
                s_w[tid * 4 + 0] = -2.0f * w.x;
                s_w[tid * 4 + 1] = -2.0f * w.y;
                s_w[tid * 4 + 2] = -2.0f * w.z;
                s_w[tid * 4 + 3] = -2.0f * w.w;
            }
        }
        __syncthreads();
        #pragma unroll
        for (int i = 0; i < 16; ++i) {
            const int h4 = i << 2;
            const float4 W4 = *(const float4*)&s_w[h4];
            const float4 Q0 = *(const float4*)&s_q[ty][h4];
            const float4 Q1 = *(const float4*)&s_q[ty + 16][h4];
            const float4 K0 = *(const float4*)&s_k[tx][h4];
            const float4 K1 = *(const float4*)&s_k[tx + 16][h4];
            quad_acc(a00, Q0, K0, W4);
            quad_acc(a01, Q0, K1, W4);
            quad_acc(a10, Q1, K0, W4);
            quad_acc(a11, Q1, K1, W4);
        }
        __syncthreads();
    }

    const size_t r0 = ((size_t)b * NQ + qb + ty) * NK;
    const size_t r1 = ((size_t)b * NQ + qb + ty + 16) * NK;
    scores[r0 + kb + tx]      = a00;
    scores[r0 + kb + tx + 16] = a01;
    scores[r1 + kb + tx]      = a10;
    scores[r1 + kb + tx + 16] = a11;
}

// ---------------------------------------------------------------------------
// softmax over k with mask k < valid_lens[b]; in-place. 1 block/row.
// ---------------------------------------------------------------------------
__global__ __launch_bounds__(256) void softmax_kernel(float* __restrict__ scores,
                                                      const int* __restrict__ valid_lens)
{
    const int row = blockIdx.x;          // 0 .. B*NQ-1
    const int b = row >> 7;              // NQ = 128
    const int valid = valid_lens[b];
    float* s = scores + (size_t)row * NK;
    const int tid = threadIdx.x;

    float4 v = *(const float4*)&s[tid * 4];
    float x[4] = {v.x, v.y, v.z, v.w};
    #pragma unroll
    for (int j = 0; j < 4; ++j) {
        const int k = tid * 4 + j;
        if (k >= valid) x[j] = -1e6f;
    }
    float m = fmaxf(fmaxf(x[0], x[1]), fmaxf(x[2], x[3]));
    #pragma unroll
    for (int off = 32; off >= 1; off >>= 1)
        m = fmaxf(m, __shfl_xor(m, off));

    __shared__ float redm[4], reds[4];
    const int wid = tid >> 6, lane = tid & 63;
    if (lane == 0) redm[wid] = m;
    __syncthreads();
    m = fmaxf(fmaxf(redm[0], redm[1]), fmaxf(redm[2], redm[3]));

    float p[4], psum = 0.f;
    #pragma unroll
    for (int j = 0; j < 4; ++j) { p[j] = __expf(x[j] - m); psum += p[j]; }
    #pragma unroll
    for (int off = 32; off >= 1; off >>= 1)
        psum += __shfl_xor(psum, off);
    if (lane == 0) reds[wid] = psum;
    __syncthreads();
    const float total = reds[0] + reds[1] + reds[2] + reds[3];
    const float inv = 1.0f / total;

    float4 o = {p[0] * inv, p[1] * inv, p[2] * inv, p[3] * inv};
    *(float4*)&s[tid * 4] = o;
}

// ---------------------------------------------------------------------------
// pv_partial: partial[ks][b,q,v] = sum_{k in slice ks} attn[b,q,k]*values[b,k,v]
// ---------------------------------------------------------------------------
__global__ __launch_bounds__(256) void pv_partial(const float* __restrict__ attn,
                                                  const float* __restrict__ values,
                                                  float* __restrict__ partial)
{
    __shared__ float s_a[16][128];
    const int tid = threadIdx.x;
    const int ks = blockIdx.x, qg = blockIdx.y, b = blockIdx.z;
    const int q0 = qg * 16;
    const int k0 = ks * 128;

    #pragma unroll
    for (int f0 = 0; f0 < 2; ++f0) {
        const int f = tid + f0 * 256;
        const int row = f >> 5;
        const int col = (f & 31) << 2;
        *(float4*)&s_a[row][col] =
            *(const float4*)&attn[((size_t)b * NQ + q0 + row) * NK + k0 + col];
    }
    __syncthreads();

    float acc[16] = {};
    #pragma unroll 8
    for (int k = 0; k < 128; ++k) {
        const float va = values[((size_t)b * NK + k0 + k) * DV + tid];
        #pragma unroll
        for (int q = 0; q < 16; ++q)
            acc[q] = fmaf(s_a[q][k], va, acc[q]);
    }

    const size_t pbase = (size_t)ks * (B * NQ * DV) + ((size_t)b * NQ + q0) * DV + tid;
    #pragma unroll
    for (int q = 0; q < 16; ++q)
        partial[pbase + (size_t)q * DV] = acc[q];
}

__global__ __launch_bounds__(256) void reduce_pv(const float* __restrict__ partial,
                                                 float* __restrict__ out)
{
    const int i = blockIdx.x * 256 + threadIdx.x;
    float s = 0.f;
    #pragma unroll
    for (int p = 0; p < 8; ++p) s += partial[(size_t)p * (B * NQ * DV) + i];
    out[i] = s;
}

// ---------------------------------------------------------------------------
extern "C" void kernel_launch(void* const* d_in, const int* in_sizes, int n_in,
                              void* d_out, int out_size, void* d_ws, size_t ws_size,
                              hipStream_t stream) {
    const float* queries    = (const float*)d_in[0];
    const float* keys       = (const float*)d_in[1];
    const float* values     = (const float*)d_in[2];
    const int*   valid_lens = (const int*)  d_in[3];
    const float* Wq         = (const float*)d_in[4];
    const float* Wk         = (const float*)d_in[5];
    const float* wv         = (const float*)d_in[6];
    float* out = (float*)d_out;

    float* ws      = (float*)d_ws;
    float* Eq      = ws;                            // B*NQ*HD = 131072
    float* Ek      = Eq + (size_t)B * NQ * HD;      // B*NK*HD = 1048576
    float* scores  = Ek + (size_t)B * NK * HD;      // B*NQ*NK = 524288
    float* partial = scores + (size_t)B * NQ * NK;  // 8*B*NQ*DV = 1048576

    proj_exp<<<dim3((B * NK) / 64, HD / 64, 2), 256, 0, stream>>>(
        queries, keys, Wq, Wk, Eq, Ek);
    scores_kernel<<<dim3(NK / 32, NQ / 32, B), 256, 0, stream>>>(Eq, Ek, wv, scores);
    softmax_kernel<<<dim3(B * NQ), 256, 0, stream>>>(scores, valid_lens);
    pv_partial<<<dim3(8, NQ / 16, B), 256, 0, stream>>>(scores, values, partial);
    reduce_pv<<<dim3((B * NQ * DV) / 256), 256, 0, stream>>>(partial, out);
}